// Round 7
// baseline (47.171 us; speedup 1.0000x reference)
//
#include <hip/hip_runtime.h>
#include <math.h>

// B=64, C=3, H=W=256 fixed by the reference problem.
#define BATCH 64
#define CH 3
#define IMH 256
#define IMW 256
#define HW (IMH * IMW)
#define NXCD 8

// 32x128 output tile (tall-narrow minimizes staged rows per output row):
// rows <= |id_|max*31 + ie_max*127 + 3 = 24.45 + 155.8 + 3 < 184.
// cols <= 31*c + 1 tap + 1 + 3 align slack <= 36.
#define NRMAX 184
#define XW 36
#define XW4 9          // float4 per staged row
#define LDSF (NRMAX * XW)   // 6624 floats = 26.5 KB
#define NPF 7          // prefetch regs: ceil(184*9/256) = 7

__device__ __forceinline__ int clampi(int v, int lo, int hi) {
    return min(max(v, lo), hi);
}

__global__ __launch_bounds__(256, 4) void TCR_52536039964687_warp(
    const float* __restrict__ img,
    const float* __restrict__ rnd,
    float* __restrict__ out) {
    __shared__ float lds[LDSF];

    // 1024 blocks = 64 images x 16 tiles (8 in x (32 wide), 2 in y (128 tall)).
    // XCD-affinity swizzle: all 16 tiles of image b land on XCD b%8.
    int w = blockIdx.x;
    int xcd = w & (NXCD - 1);
    int t = w >> 3;                  // 0..127 within XCD
    int b = ((t >> 4) << 3) | xcd;   // image index
    int tile = t & 15;
    int X0 = (tile & 7) << 5;        // tile col origin (32-wide)
    int Y0 = (tile >> 3) << 7;       // tile row origin (128-tall)

    int tid = threadIdx.x;
    int dx = tid & 31;               // output col within tile
    int qy = tid >> 5;               // 0..7 row phase; rows Y0+qy+8k, k<16

    // ---- per-image inverse affine coefficients (simplified; a==0 exactly) ----
    const float r = rnd[b];
    const float ANG  = 0.34906585039886590f;   // deg2rad(20)
    const float ANG2 = 0.69813170079773179f;   // 2*ANG
    const float Wc = (float)IMH;
    const float Hc = (float)IMW;

    float tx  = 12.0f * r - 6.0f;
    float ty  = tx;
    float rho = ANG2 * r - ANG;

    float s = __sinf(rho);
    float c = __cosf(rho);            // 0.9397 <= c <= 1.0
    float cb = 2.f * c * c - 1.f;     // cos(2*rho) >= 0.766
    float sb = 2.f * s * c;           // sin(2*rho)
    float rcb = 1.f / cb;

    float ic  = 0.5f * Wc * (1.f - c) - tx;
    float id_ = -sb * c * rcb;        // |id_| <= 0.7885
    float ie  = c * rcb;              // 1.0 <= ie <= 1.2267
    float P   = 0.5f * (Wc * c - Wc + 2.f * tx);
    float Q   = 0.5f * (Hc * c - Wc * cb + 2.f * ty * cb - Wc * sb + 2.f * tx * sb);
    float if_ = (sb * P - Q) * rcb;
    // sx = fmaf(c, x, ic); sy = fmaf(id_, x, fmaf(ie, y, if_))

    // ---- tile source bounds via corners (same fmaf composition as below;
    //      fma monotone per operand, c>0, ie>0 -> corners bound the tile) ----
    float X0f = (float)X0, X1f = (float)(X0 + 31);
    float Y0f = (float)Y0, Y1f = (float)(Y0 + 127);
    float sxlo = fmaf(c, X0f, ic);
    int lxmin = clampi((int)floorf(sxlo), 0, IMW - 2);
    int axlo = lxmin & ~3;            // 16B-aligned staging origin

    float g0 = fmaf(ie, Y0f, if_);
    float g1 = fmaf(ie, Y1f, if_);    // g1 >= g0
    float syA = fmaf(id_, X0f, g0), syB = fmaf(id_, X1f, g0);
    float syC = fmaf(id_, X0f, g1), syD = fmaf(id_, X1f, g1);
    float symin = fminf(fminf(syA, syB), fminf(syC, syD));
    float symax = fmaxf(fmaxf(syA, syB), fmaxf(syC, syD));
    int rlo = clampi((int)floorf(symin), 0, IMH - 1);
    int rhi = clampi((int)floorf(symax) + 1, 0, IMH - 1);
    int NR = rhi - rlo + 1;           // <= 184 by construction
    int nq = NR * XW4;                // float4 slots to stage (<= 1656)

    // ---- per-thread x taps (channel- and row-invariant) ----
    float fx = (float)(X0 + dx);
    float sx = fmaf(c, fx, ic);
    float x0f = floorf(sx);
    int x0 = (int)x0f;
    float wx = sx - x0f;
    int lx = clampi(x0, 0, IMW - 2);  // (lx,lx+1) provably inside staged cols
    float wl = (x0 == lx) ? (1.f - wx) : ((x0 == lx - 1) ? wx : 0.f);
    float wh = (x0 == lx) ? wx : ((x0 == lx + 1) ? (1.f - wx) : 0.f);
    int px = lx - axlo;               // 0..34

    // ---- per-thread y taps: 16 rows (Y0+qy+8k), packed addresses ----
    int   a01[16];                    // lo16 = word addr of (r0,px), hi16 = (r1,px)
    float wy0[16], wy1[16];
    #pragma unroll
    for (int k = 0; k < 16; ++k) {
        float fy = (float)(Y0 + qy + 8 * k);
        float sy = fmaf(id_, fx, fmaf(ie, fy, if_));
        float y0f = floorf(sy);
        int y0 = (int)y0f;
        int y1 = y0 + 1;
        float wy = sy - y0f;
        wy0[k] = ((y0 >= 0) & (y0 < IMH)) ? (1.f - wy) : 0.f;
        wy1[k] = ((y1 >= 0) & (y1 < IMH)) ? wy : 0.f;
        // clamp is monotone -> staged window [rlo,rhi] contains both rows
        int a0 = (clampi(y0, 0, IMH - 1) - rlo) * XW + px;   // < 6624 < 2^16
        int a1 = (clampi(y1, 0, IMH - 1) - rlo) * XW + px;
        a01[k] = a0 | (a1 << 16);
    }

    const float* ibase = img + (size_t)b * CH * HW;
    float* obase = out + (size_t)b * CH * HW + (Y0 + qy) * IMW + X0 + dx;

    float4 pre[NPF];   // fully-unrolled static indexing -> stays in VGPRs

    #define PREFETCH(ch_) {                                                   \
        const float* cbase = ibase + (ch_) * HW;                              \
        _Pragma("unroll")                                                     \
        for (int it = 0; it < NPF; ++it) {                                    \
            int e = tid + it * 256;                                           \
            if (e < nq) {                                                     \
                unsigned row = (unsigned)e / XW4;                             \
                int q = e - (int)row * XW4;                                   \
                int gq = min(axlo + 4 * q, IMW - 4); /* clamped quads are    \
                      never sampled: sampled p <= 255-axlo < 256-axlo */      \
                pre[it] = *(const float4*)(cbase + (rlo + (int)row) * IMW + gq);\
            }                                                                 \
        }                                                                     \
    }

    #define WRITE_STAGE() {                                                   \
        _Pragma("unroll")                                                     \
        for (int it = 0; it < NPF; ++it) {                                    \
            int e = tid + it * 256;                                           \
            if (e < nq) {                                                     \
                unsigned row = (unsigned)e / XW4;                             \
                int q = e - (int)row * XW4;                                   \
                *((float4*)&lds[row * XW + 4 * q]) = pre[it];                 \
            }                                                                 \
        }                                                                     \
    }

    #define SAMPLE(ch_) {                                                     \
        _Pragma("unroll")                                                     \
        for (int k = 0; k < 16; ++k) {                                        \
            int a0 = a01[k] & 0xffff;                                         \
            int a1 = a01[k] >> 16;                                            \
            float l00 = lds[a0], l01 = lds[a0 + 1];                           \
            float l10 = lds[a1], l11 = lds[a1 + 1];                           \
            float v = (l00 * wl + l01 * wh) * wy0[k]                          \
                    + (l10 * wl + l11 * wh) * wy1[k];                         \
            __builtin_nontemporal_store(v, obase + (ch_) * HW + 8 * k * IMW); \
        }                                                                     \
    }

    // ---- 5-barrier single-buffer channel pipeline (T14 async-stage):
    // next channel's global loads are in flight during SAMPLE of current.
    PREFETCH(0);
    WRITE_STAGE();              // compiler waits only pre[0]'s vmcnt
    __syncthreads();
    PREFETCH(1);                // latency hides under SAMPLE(0)
    SAMPLE(0);
    __syncthreads();            // all lanes done reading lds
    WRITE_STAGE();              // pre[1] -> lds
    __syncthreads();
    PREFETCH(2);                // hides under SAMPLE(1)
    SAMPLE(1);
    __syncthreads();
    WRITE_STAGE();
    __syncthreads();
    SAMPLE(2);

    #undef PREFETCH
    #undef WRITE_STAGE
    #undef SAMPLE
}

extern "C" void kernel_launch(void* const* d_in, const int* in_sizes, int n_in,
                              void* d_out, int out_size, void* d_ws, size_t ws_size,
                              hipStream_t stream) {
    const float* img = (const float*)d_in[0];
    const float* rnd = (const float*)d_in[1];
    float* out = (float*)d_out;
    (void)d_ws; (void)ws_size;

    hipLaunchKernelGGL(TCR_52536039964687_warp, dim3(BATCH * 16), dim3(256), 0, stream,
                       img, rnd, out);
}

// Round 8
// 25.759 us; speedup vs baseline: 1.8313x; 1.8313x over previous
//
#include <hip/hip_runtime.h>
#include <math.h>

// B=64, C=3, H=W=256 fixed by the reference problem.
#define BATCH 64
#define CH 3
#define IMH 256
#define IMW 256
#define HW (IMH * IMW)
#define NXCD 8

// R4 geometry (proven 26.1 us): 64x64 output tile, single LDS buffer.
// Row span bound: (|id_|max + ie_max)*63 + 2 = (0.7885+1.2267)*63+2 < 130.
#define NRMAX 132
#define XW 68          // staged cols (63*c + hi tap + align slack + 1)
#define XW4 17         // float4 per staged row
#define NQMAX 2304     // 9 * 256 staging quads (>= 132*17=2244), padded
// LDS = 2304 * 16 B = 36 KB -> 4 blocks/CU.

#define AS1 __attribute__((address_space(1)))
#define AS3 __attribute__((address_space(3)))

__device__ __forceinline__ int clampi(int v, int lo, int hi) {
    return min(max(v, lo), hi);
}

__global__ __launch_bounds__(256, 4) void TCR_52536039964687_warp(
    const float* __restrict__ img,
    const float* __restrict__ rnd,
    float* __restrict__ out) {
    __shared__ float4 lds4[NQMAX];          // 36 KB
    float* lds = (float*)lds4;

    // 1024 blocks = 64 images x 16 tiles (4x4 of 64x64).
    // XCD-affinity swizzle: all 16 tiles of image b land on XCD b%8.
    int w = blockIdx.x;
    int xcd = w & (NXCD - 1);
    int t = w >> 3;                  // 0..127 within XCD
    int b = ((t >> 4) << 3) | xcd;   // image index
    int tile = t & 15;
    int X0 = (tile & 3) << 6;        // tile col origin
    int Y0 = (tile >> 2) << 6;       // tile row origin

    int tid = threadIdx.x;
    int dx = tid & 63;               // output col within tile
    int qy = tid >> 6;               // 0..3 row phase; rows Y0+qy+4k, k<16

    // ---- per-image inverse affine coefficients (simplified; a==0 exactly) ----
    const float r = rnd[b];
    const float ANG  = 0.34906585039886590f;   // deg2rad(20)
    const float ANG2 = 0.69813170079773179f;   // 2*ANG
    const float Wc = (float)IMH;
    const float Hc = (float)IMW;

    float tx  = 12.0f * r - 6.0f;
    float ty  = tx;
    float rho = ANG2 * r - ANG;

    float s = __sinf(rho);
    float c = __cosf(rho);            // 0.9397 <= c <= 1.0
    float cb = 2.f * c * c - 1.f;     // cos(2*rho) >= 0.766
    float sb = 2.f * s * c;           // sin(2*rho)
    float rcb = 1.f / cb;

    float ic  = 0.5f * Wc * (1.f - c) - tx;
    float id_ = -sb * c * rcb;        // |id_| <= 0.7885
    float ie  = c * rcb;              // 1.0 <= ie <= 1.2267
    float P   = 0.5f * (Wc * c - Wc + 2.f * tx);
    float Q   = 0.5f * (Hc * c - Wc * cb + 2.f * ty * cb - Wc * sb + 2.f * tx * sb);
    float if_ = (sb * P - Q) * rcb;
    // sx = fmaf(c, x, ic); sy = fmaf(id_, x, fmaf(ie, y, if_))

    // ---- tile source bounds via corners (same fmaf composition as below;
    //      fma monotone per operand, c>0, ie>0 -> corners bound the tile) ----
    float X0f = (float)X0, X1f = (float)(X0 + 63);
    float Y0f = (float)Y0, Y1f = (float)(Y0 + 63);
    float sxlo = fmaf(c, X0f, ic);
    int lxmin = clampi((int)floorf(sxlo), 0, IMW - 2);
    int axlo = lxmin & ~3;            // 16B-aligned staging origin

    float g0 = fmaf(ie, Y0f, if_);
    float g1 = fmaf(ie, Y1f, if_);    // g1 >= g0
    float syA = fmaf(id_, X0f, g0), syB = fmaf(id_, X1f, g0);
    float syC = fmaf(id_, X0f, g1), syD = fmaf(id_, X1f, g1);
    float symin = fminf(fminf(syA, syB), fminf(syC, syD));
    float symax = fmaxf(fmaxf(syA, syB), fmaxf(syC, syD));
    int rlo = clampi((int)floorf(symin), 0, IMH - 1);
    int rhi = clampi((int)floorf(symax) + 1, 0, IMH - 1);
    int NR = rhi - rlo + 1;           // <= 130 by construction

    // ---- per-thread x taps (channel- and row-invariant) ----
    float fx = (float)(X0 + dx);
    float sx = fmaf(c, fx, ic);
    float x0f = floorf(sx);
    int x0 = (int)x0f;
    float wx = sx - x0f;
    int lx = clampi(x0, 0, IMW - 2);  // (lx,lx+1) provably inside staged cols
    float wl = (x0 == lx) ? (1.f - wx) : ((x0 == lx - 1) ? wx : 0.f);
    float wh = (x0 == lx) ? wx : ((x0 == lx + 1) ? (1.f - wx) : 0.f);
    int px = lx - axlo;               // 0..66

    // ---- per-thread y taps: 16 rows (Y0+qy+4k), packed word addresses ----
    int   a01[16];                    // lo16 = (r0,px) word addr, hi16 = (r1,px)
    float wy0[16], wy1[16];
    #pragma unroll
    for (int k = 0; k < 16; ++k) {
        float fy = (float)(Y0 + qy + 4 * k);
        float sy = fmaf(id_, fx, fmaf(ie, fy, if_));
        float y0f = floorf(sy);
        int y0 = (int)y0f;
        int y1 = y0 + 1;
        float wy = sy - y0f;
        wy0[k] = ((y0 >= 0) & (y0 < IMH)) ? (1.f - wy) : 0.f;
        wy1[k] = ((y1 >= 0) & (y1 < IMH)) ? wy : 0.f;
        // clamp is monotone -> staged window [rlo,rhi] contains both rows
        int a0 = (clampi(y0, 0, IMH - 1) - rlo) * XW + px;   // < 8976 < 2^16
        int a1 = (clampi(y1, 0, IMH - 1) - rlo) * XW + px;
        a01[k] = a0 | (a1 << 16);
    }

    const float* ibase = img + (size_t)b * CH * HW;
    float* obase = out + (size_t)b * CH * HW + (Y0 + qy) * IMW + X0 + dx;

    // Stage channel ch via async global->LDS (no VGPR transit, no spills).
    // LDS layout is exactly wave-linear: float offset row*68+4q == 4*e,
    // so dest byte = 16*e = wave-uniform base + lane*16. Source is per-lane.
    // All 9 iterations run full-wave: source row clamped to NR-1 (duplicate
    // L2-hit reads for the padded tail; LDS tail region is never sampled).
    #define STAGE(ch_) {                                                      \
        const float* cbase = ibase + (ch_) * HW;                              \
        _Pragma("unroll")                                                     \
        for (int it = 0; it < 9; ++it) {                                      \
            int e = tid + it * 256;                                           \
            unsigned row = (unsigned)e / XW4;                                 \
            int q = e - (int)row * XW4;                                       \
            int rr = min((int)row, NR - 1);                                   \
            int gq = min(axlo + 4 * q, IMW - 4);                              \
            const float* gp = cbase + (rlo + rr) * IMW + gq;                  \
            __builtin_amdgcn_global_load_lds((const AS1 void*)gp,             \
                                             (AS3 void*)&lds4[e], 16, 0, 0);  \
        }                                                                     \
    }

    #define SAMPLE(ch_) {                                                     \
        _Pragma("unroll")                                                     \
        for (int k = 0; k < 16; ++k) {                                        \
            int a0 = a01[k] & 0xffff;                                         \
            int a1 = a01[k] >> 16;                                            \
            float l00 = lds[a0], l01 = lds[a0 + 1];  /* ds_read2_b32 */       \
            float l10 = lds[a1], l11 = lds[a1 + 1];                           \
            float v = (l00 * wl + l01 * wh) * wy0[k]                          \
                    + (l10 * wl + l11 * wh) * wy1[k];                         \
            __builtin_nontemporal_store(v, obase + (ch_) * HW + 4 * k * IMW); \
        }                                                                     \
    }

    // ---- R4 schedule: stage; bar; sample; bar; x3 (cross-block overlap
    //      from 4 resident blocks/CU covers the stage latency) ----
    STAGE(0);
    __syncthreads();      // drains vmcnt -> LDS visible
    SAMPLE(0);
    __syncthreads();      // all lanes done reading before restage
    STAGE(1);
    __syncthreads();
    SAMPLE(1);
    __syncthreads();
    STAGE(2);
    __syncthreads();
    SAMPLE(2);

    #undef STAGE
    #undef SAMPLE
}

extern "C" void kernel_launch(void* const* d_in, const int* in_sizes, int n_in,
                              void* d_out, int out_size, void* d_ws, size_t ws_size,
                              hipStream_t stream) {
    const float* img = (const float*)d_in[0];
    const float* rnd = (const float*)d_in[1];
    float* out = (float*)d_out;
    (void)d_ws; (void)ws_size;

    hipLaunchKernelGGL(TCR_52536039964687_warp, dim3(BATCH * 16), dim3(256), 0, stream,
                       img, rnd, out);
}

// Round 9
// 24.097 us; speedup vs baseline: 1.9575x; 1.0689x over previous
//
#include <hip/hip_runtime.h>
#include <math.h>

// B=64, C=3, H=W=256 fixed by the reference problem.
#define BATCH 64
#define CH 3
#define IMH 256
#define IMW 256
#define HW (IMH * IMW)
#define NXCD 8

// 64x64 output tile, one CHANNEL per block (3072 blocks total).
// Row span bound: (|id_|max + ie_max)*63 + 2 = (0.7885+1.2267)*63+2 < 130.
#define NRMAX 132
#define XW 68          // staged cols (63*c + hi tap + align slack + 1)
#define XW4 17         // float4 per staged row
#define NQMAX 2304     // 9 * 256 staging quads (>= 132*17=2244), padded
// LDS = 2304 * 16 B = 36 KB -> 4 blocks/CU.

#define AS1 __attribute__((address_space(1)))
#define AS3 __attribute__((address_space(3)))

__device__ __forceinline__ int clampi(int v, int lo, int hi) {
    return min(max(v, lo), hi);
}

__global__ __launch_bounds__(256, 4) void TCR_52536039964687_warp(
    const float* __restrict__ img,
    const float* __restrict__ rnd,
    float* __restrict__ out) {
    __shared__ float4 lds4[NQMAX];          // 36 KB
    float* lds = (float*)lds4;

    // 3072 blocks = 64 images x 16 tiles x 3 channels.
    // XCD-affinity: all 48 blocks of image b land on XCD b%8
    // (assumes HW round-robin xcd = bid % 8; perf-only assumption).
    int w = blockIdx.x;
    int xcd = w & (NXCD - 1);
    unsigned t = (unsigned)w >> 3;   // 0..383 within XCD
    unsigned islot = t / 48u;        // image slot within XCD, 0..7
    unsigned rem = t - islot * 48u;  // 0..47
    int b = ((int)islot << 3) | xcd; // image index
    int ch = (int)(rem >> 4);        // channel 0..2
    int tile = (int)(rem & 15u);
    int X0 = (tile & 3) << 6;        // tile col origin
    int Y0 = (tile >> 2) << 6;       // tile row origin

    int tid = threadIdx.x;
    int dx = tid & 63;               // output col within tile
    int qy = tid >> 6;               // 0..3 row phase; rows Y0+qy+4k, k<16

    // ---- per-image inverse affine coefficients (simplified; a==0 exactly) ----
    const float r = rnd[b];
    const float ANG  = 0.34906585039886590f;   // deg2rad(20)
    const float ANG2 = 0.69813170079773179f;   // 2*ANG
    const float Wc = (float)IMH;
    const float Hc = (float)IMW;

    float tx  = 12.0f * r - 6.0f;
    float ty  = tx;
    float rho = ANG2 * r - ANG;

    float s = __sinf(rho);
    float c = __cosf(rho);            // 0.9397 <= c <= 1.0
    float cb = 2.f * c * c - 1.f;     // cos(2*rho) >= 0.766
    float sb = 2.f * s * c;           // sin(2*rho)
    float rcb = 1.f / cb;

    float ic  = 0.5f * Wc * (1.f - c) - tx;
    float id_ = -sb * c * rcb;        // |id_| <= 0.7885
    float ie  = c * rcb;              // 1.0 <= ie <= 1.2267
    float P   = 0.5f * (Wc * c - Wc + 2.f * tx);
    float Q   = 0.5f * (Hc * c - Wc * cb + 2.f * ty * cb - Wc * sb + 2.f * tx * sb);
    float if_ = (sb * P - Q) * rcb;
    // sx = fmaf(c, x, ic); sy = fmaf(id_, x, fmaf(ie, y, if_))

    // ---- tile source bounds via corners (same fmaf composition as below;
    //      fma monotone per operand, c>0, ie>0 -> corners bound the tile) ----
    float X0f = (float)X0, X1f = (float)(X0 + 63);
    float Y0f = (float)Y0, Y1f = (float)(Y0 + 63);
    float sxlo = fmaf(c, X0f, ic);
    int lxmin = clampi((int)floorf(sxlo), 0, IMW - 2);
    int axlo = lxmin & ~3;            // 16B-aligned staging origin

    float g0 = fmaf(ie, Y0f, if_);
    float g1 = fmaf(ie, Y1f, if_);    // g1 >= g0
    float syA = fmaf(id_, X0f, g0), syB = fmaf(id_, X1f, g0);
    float syC = fmaf(id_, X0f, g1), syD = fmaf(id_, X1f, g1);
    float symin = fminf(fminf(syA, syB), fminf(syC, syD));
    float symax = fmaxf(fmaxf(syA, syB), fmaxf(syC, syD));
    int rlo = clampi((int)floorf(symin), 0, IMH - 1);
    int rhi = clampi((int)floorf(symax) + 1, 0, IMH - 1);
    int NR = rhi - rlo + 1;           // <= 130 by construction

    // ---- STAGE FIRST: issue async global->LDS, then compute taps under
    //      the load latency; single barrier drains vmcnt before sampling.
    // LDS layout is exactly wave-linear: float offset row*68+4q == 4*e,
    // so dest byte = 16*e = wave-uniform base + lane*16. Source is per-lane.
    // Padded iterations re-read row NR-1 (L2 hits); that LDS tail region is
    // never sampled (max sampled word addr (NR-1)*68+67 < NR*68 <= 4*nq).
    {
        const float* cbase = img + (size_t)b * CH * HW + ch * HW;
        #pragma unroll
        for (int it = 0; it < 9; ++it) {
            int e = tid + it * 256;
            unsigned row = (unsigned)e / XW4;
            int q = e - (int)row * XW4;
            int rr = min((int)row, NR - 1);
            int gq = min(axlo + 4 * q, IMW - 4);
            const float* gp = cbase + (rlo + rr) * IMW + gq;
            __builtin_amdgcn_global_load_lds((const AS1 void*)gp,
                                             (AS3 void*)&lds4[e], 16, 0, 0);
        }
    }

    // ---- per-thread x taps (row-invariant) ----
    float fx = (float)(X0 + dx);
    float sx = fmaf(c, fx, ic);
    float x0f = floorf(sx);
    int x0 = (int)x0f;
    float wx = sx - x0f;
    int lx = clampi(x0, 0, IMW - 2);  // (lx,lx+1) provably inside staged cols
    float wl = (x0 == lx) ? (1.f - wx) : ((x0 == lx - 1) ? wx : 0.f);
    float wh = (x0 == lx) ? wx : ((x0 == lx + 1) ? (1.f - wx) : 0.f);
    int px = lx - axlo;               // 0..66

    // ---- per-thread y taps: 16 rows (Y0+qy+4k), packed word addresses ----
    int   a01[16];                    // lo16 = (r0,px) word addr, hi16 = (r1,px)
    float wy0[16], wy1[16];
    #pragma unroll
    for (int k = 0; k < 16; ++k) {
        float fy = (float)(Y0 + qy + 4 * k);
        float sy = fmaf(id_, fx, fmaf(ie, fy, if_));
        float y0f = floorf(sy);
        int y0 = (int)y0f;
        int y1 = y0 + 1;
        float wy = sy - y0f;
        wy0[k] = ((y0 >= 0) & (y0 < IMH)) ? (1.f - wy) : 0.f;
        wy1[k] = ((y1 >= 0) & (y1 < IMH)) ? wy : 0.f;
        // clamp is monotone -> staged window [rlo,rhi] contains both rows
        int a0 = (clampi(y0, 0, IMH - 1) - rlo) * XW + px;   // < 8976 < 2^16
        int a1 = (clampi(y1, 0, IMH - 1) - rlo) * XW + px;
        a01[k] = a0 | (a1 << 16);
    }

    __syncthreads();      // drains vmcnt -> staged LDS visible

    float* obase = out + (size_t)b * CH * HW + ch * HW
                 + (Y0 + qy) * IMW + X0 + dx;
    #pragma unroll
    for (int k = 0; k < 16; ++k) {
        int a0 = a01[k] & 0xffff;
        int a1 = a01[k] >> 16;
        float l00 = lds[a0], l01 = lds[a0 + 1];   // ds_read2_b32
        float l10 = lds[a1], l11 = lds[a1 + 1];
        float v = (l00 * wl + l01 * wh) * wy0[k]
                + (l10 * wl + l11 * wh) * wy1[k];
        __builtin_nontemporal_store(v, obase + 4 * k * IMW);
    }
}

extern "C" void kernel_launch(void* const* d_in, const int* in_sizes, int n_in,
                              void* d_out, int out_size, void* d_ws, size_t ws_size,
                              hipStream_t stream) {
    const float* img = (const float*)d_in[0];
    const float* rnd = (const float*)d_in[1];
    float* out = (float*)d_out;
    (void)d_ws; (void)ws_size;

    hipLaunchKernelGGL(TCR_52536039964687_warp, dim3(BATCH * 16 * CH), dim3(256),
                       0, stream, img, rnd, out);
}

// Round 10
// 23.956 us; speedup vs baseline: 1.9691x; 1.0059x over previous
//
#include <hip/hip_runtime.h>
#include <math.h>

// B=64, C=3, H=W=256 fixed by the reference problem.
#define BATCH 64
#define CH 3
#define IMH 256
#define IMW 256
#define HW (IMH * IMW)
#define NXCD 8

// 32x128 output tile (tall-narrow minimizes staged words per output:
// 184*36/4096 = 1.62 vs 2.16 for 64x64), one CHANNEL per block.
// Row span bound: |id_|max*31 + ie_max*127 + 3 = 24.45 + 155.8 + 3 < 184.
// Col bound: ceil(31*c) + 1 tap + 3 align slack + 1 <= 36.
#define NRMAX 184
#define XW 36
#define XW4 9            // float4 per staged row
#define NQ (NRMAX * XW4) // 1656 staging quads = 26.5 KB -> 6 blocks/CU
#define NIT 7            // ceil(1656/256)

#define AS1 __attribute__((address_space(1)))
#define AS3 __attribute__((address_space(3)))

__device__ __forceinline__ int clampi(int v, int lo, int hi) {
    return min(max(v, lo), hi);
}

__global__ __launch_bounds__(256, 6) void TCR_52536039964687_warp(
    const float* __restrict__ img,
    const float* __restrict__ rnd,
    float* __restrict__ out) {
    __shared__ float4 lds4[NQ];             // 26.5 KB
    float* lds = (float*)lds4;

    // 3072 blocks = 64 images x 16 tiles (8 in x, 2 in y) x 3 channels.
    // XCD-affinity: all 48 blocks of image b land on XCD b%8
    // (assumes HW round-robin xcd = bid % 8; perf-only assumption).
    int w = blockIdx.x;
    int xcd = w & (NXCD - 1);
    unsigned t = (unsigned)w >> 3;   // 0..383 within XCD
    unsigned islot = t / 48u;        // image slot within XCD, 0..7
    unsigned rem = t - islot * 48u;  // 0..47
    int b = ((int)islot << 3) | xcd; // image index
    int ch = (int)(rem >> 4);        // channel 0..2
    int tile = (int)(rem & 15u);
    int X0 = (tile & 7) << 5;        // tile col origin (32-wide)
    int Y0 = (tile >> 3) << 7;       // tile row origin (128-tall)

    int tid = threadIdx.x;
    int dx = tid & 31;               // output col within tile
    int qy = tid >> 5;               // 0..7 row phase; rows Y0+qy+8k, k<16

    // ---- per-image inverse affine coefficients (simplified; a==0 exactly) ----
    const float r = rnd[b];
    const float ANG  = 0.34906585039886590f;   // deg2rad(20)
    const float ANG2 = 0.69813170079773179f;   // 2*ANG
    const float Wc = (float)IMH;
    const float Hc = (float)IMW;

    float tx  = 12.0f * r - 6.0f;
    float ty  = tx;
    float rho = ANG2 * r - ANG;

    float s = __sinf(rho);
    float c = __cosf(rho);            // 0.9397 <= c <= 1.0
    float cb = 2.f * c * c - 1.f;     // cos(2*rho) >= 0.766
    float sb = 2.f * s * c;           // sin(2*rho)
    float rcb = 1.f / cb;

    float ic  = 0.5f * Wc * (1.f - c) - tx;
    float id_ = -sb * c * rcb;        // |id_| <= 0.7885
    float ie  = c * rcb;              // 1.0 <= ie <= 1.2267
    float P   = 0.5f * (Wc * c - Wc + 2.f * tx);
    float Q   = 0.5f * (Hc * c - Wc * cb + 2.f * ty * cb - Wc * sb + 2.f * tx * sb);
    float if_ = (sb * P - Q) * rcb;
    // sx = fmaf(c, x, ic); sy = fmaf(id_, x, fmaf(ie, y, if_))

    // ---- tile source bounds via corners (same fmaf composition as below;
    //      fma monotone per operand, c>0, ie>0 -> corners bound the tile) ----
    float X0f = (float)X0, X1f = (float)(X0 + 31);
    float Y0f = (float)Y0, Y1f = (float)(Y0 + 127);
    float sxlo = fmaf(c, X0f, ic);
    int lxmin = clampi((int)floorf(sxlo), 0, IMW - 2);
    int axlo = lxmin & ~3;            // 16B-aligned staging origin

    float g0 = fmaf(ie, Y0f, if_);
    float g1 = fmaf(ie, Y1f, if_);    // g1 >= g0
    float syA = fmaf(id_, X0f, g0), syB = fmaf(id_, X1f, g0);
    float syC = fmaf(id_, X0f, g1), syD = fmaf(id_, X1f, g1);
    float symin = fminf(fminf(syA, syB), fminf(syC, syD));
    float symax = fmaxf(fmaxf(syA, syB), fmaxf(syC, syD));
    int rlo = clampi((int)floorf(symin), 0, IMH - 1);
    int rhi = clampi((int)floorf(symax) + 1, 0, IMH - 1);
    int NR = rhi - rlo + 1;           // <= 184 by construction
    int nq = NR * XW4;                // quads actually needed (<= 1656)

    // ---- STAGE FIRST: issue async global->LDS, predicated on e < nq
    //      (no wasted tail loads); taps computed under the load latency;
    //      one barrier drains vmcnt before sampling.
    // LDS layout is exactly wave-linear: float offset row*36+4q == 4*e,
    // so dest byte = 16*e = wave-uniform base + lane*16. Source is per-lane.
    // Quads clamped to gq=IMW-4 are never sampled: any sampled float f<=255
    // has its quad base axlo+4q <= 252 (proof: f&~3 <= 252).
    {
        const float* cbase = img + (size_t)b * CH * HW + ch * HW;
        #pragma unroll
        for (int it = 0; it < NIT; ++it) {
            int e = tid + it * 256;
            if (e < nq) {
                unsigned row = (unsigned)e / XW4;
                int q = e - (int)row * XW4;
                int gq = min(axlo + 4 * q, IMW - 4);
                const float* gp = cbase + (rlo + (int)row) * IMW + gq;
                __builtin_amdgcn_global_load_lds((const AS1 void*)gp,
                                                 (AS3 void*)&lds4[e], 16, 0, 0);
            }
        }
    }

    // ---- per-thread x taps (row-invariant) ----
    float fx = (float)(X0 + dx);
    float sx = fmaf(c, fx, ic);
    float x0f = floorf(sx);
    int x0 = (int)x0f;
    float wx = sx - x0f;
    int lx = clampi(x0, 0, IMW - 2);  // (lx,lx+1) provably inside staged cols
    float wl = (x0 == lx) ? (1.f - wx) : ((x0 == lx - 1) ? wx : 0.f);
    float wh = (x0 == lx) ? wx : ((x0 == lx + 1) ? (1.f - wx) : 0.f);
    int px = lx - axlo;               // 0..34

    // ---- per-thread y taps: 16 rows (Y0+qy+8k), packed word addresses ----
    int   a01[16];                    // lo16 = (r0,px) word addr, hi16 = (r1,px)
    float wy0[16], wy1[16];
    #pragma unroll
    for (int k = 0; k < 16; ++k) {
        float fy = (float)(Y0 + qy + 8 * k);
        float sy = fmaf(id_, fx, fmaf(ie, fy, if_));
        float y0f = floorf(sy);
        int y0 = (int)y0f;
        int y1 = y0 + 1;
        float wy = sy - y0f;
        wy0[k] = ((y0 >= 0) & (y0 < IMH)) ? (1.f - wy) : 0.f;
        wy1[k] = ((y1 >= 0) & (y1 < IMH)) ? wy : 0.f;
        // clamp is monotone -> staged window [rlo,rhi] contains both rows
        int a0 = (clampi(y0, 0, IMH - 1) - rlo) * XW + px;   // < 6624 < 2^16
        int a1 = (clampi(y1, 0, IMH - 1) - rlo) * XW + px;
        a01[k] = a0 | (a1 << 16);
    }

    __syncthreads();      // drains vmcnt -> staged LDS visible

    float* obase = out + (size_t)b * CH * HW + ch * HW
                 + (Y0 + qy) * IMW + X0 + dx;
    #pragma unroll
    for (int k = 0; k < 16; ++k) {
        int a0 = a01[k] & 0xffff;
        int a1 = a01[k] >> 16;
        float l00 = lds[a0], l01 = lds[a0 + 1];   // ds_read2_b32
        float l10 = lds[a1], l11 = lds[a1 + 1];
        float v = (l00 * wl + l01 * wh) * wy0[k]
                + (l10 * wl + l11 * wh) * wy1[k];
        __builtin_nontemporal_store(v, obase + 8 * k * IMW);
    }
}

extern "C" void kernel_launch(void* const* d_in, const int* in_sizes, int n_in,
                              void* d_out, int out_size, void* d_ws, size_t ws_size,
                              hipStream_t stream) {
    const float* img = (const float*)d_in[0];
    const float* rnd = (const float*)d_in[1];
    float* out = (float*)d_out;
    (void)d_ws; (void)ws_size;

    hipLaunchKernelGGL(TCR_52536039964687_warp, dim3(BATCH * 16 * CH), dim3(256),
                       0, stream, img, rnd, out);
}